// Round 5
// baseline (863.176 us; speedup 1.0000x reference)
//
#include <hip/hip_runtime.h>
#include <cmath>

#define N_NODES   100000
#define N_EDGES   3200000
#define D_FEAT    512
#define HIDDEN    16
#define N_CLASSES 7

#define NCHUNK 391                   // pass-1 blocks, 8192 edges each
#define CHUNK  8192
#define NBKT   1563                  // buckets of 64 nodes (dst>>6); 1563*64 >= 100000
#define NSCAN  (NBKT * NCHUNK)       // 611,133
#define NSB1   ((NSCAN + 255) / 256) // 2388
#define NSB2   ((NSB1 + 255) / 256)  // 10

typedef __attribute__((ext_vector_type(4))) float  f32x4;
typedef __attribute__((ext_vector_type(8))) short  bf16x8;

__device__ __forceinline__ short f2bf(float f) {
    union { float f; unsigned u; } v; v.f = f;
    unsigned r = v.u + 0x7fffu + ((v.u >> 16) & 1u);   // RNE
    return (short)(r >> 16);
}

// ---------------- pass 1a: per-chunk bucket histogram (LDS atomics only) ---
__global__ __launch_bounds__(256) void k_hist1(const int* __restrict__ dst,
                                               unsigned* __restrict__ hist) {
    __shared__ unsigned h[NBKT];
    int t = threadIdx.x, b = blockIdx.x;
    for (int i = t; i < NBKT; i += 256) h[i] = 0u;
    __syncthreads();
    int base = b * CHUNK;
    #pragma unroll 4
    for (int k = 0; k < 32; ++k) {
        int e = base + k * 256 + t;
        if (e < N_EDGES) atomicAdd(&h[((unsigned)dst[e]) >> 6], 1u);
    }
    __syncthreads();
    for (int i = t; i < NBKT; i += 256)
        hist[(size_t)i * NCHUNK + b] = h[i];   // bin-major for global scan
}

// ---------------- generic exclusive-scan building blocks -------------------
__global__ __launch_bounds__(256) void k_scan_blocks(const unsigned* __restrict__ in,
                                                     unsigned* __restrict__ out_excl,
                                                     unsigned* __restrict__ part, int n) {
    __shared__ unsigned t0[256];
    int t = threadIdx.x, i = blockIdx.x * 256 + t;
    unsigned v = (i < n) ? in[i] : 0u;
    t0[t] = v; __syncthreads();
    #pragma unroll
    for (int off = 1; off < 256; off <<= 1) {
        unsigned add = (t >= off) ? t0[t - off] : 0u;
        __syncthreads();
        t0[t] += add;
        __syncthreads();
    }
    if (i < n) out_excl[i] = t0[t] - v;
    if (t == 255) part[blockIdx.x] = t0[t];
}

__global__ __launch_bounds__(1024) void k_scan_part(unsigned* __restrict__ part,
                                                    unsigned* __restrict__ part_scan,
                                                    int nparts) {
    __shared__ unsigned t0[1024];
    int t = threadIdx.x;
    unsigned v = (t < nparts) ? part[t] : 0u;
    t0[t] = v; __syncthreads();
    #pragma unroll
    for (int off = 1; off < 1024; off <<= 1) {
        unsigned add = (t >= off) ? t0[t - off] : 0u;
        __syncthreads();
        t0[t] += add;
        __syncthreads();
    }
    if (t < nparts) part_scan[t] = t0[t] - v;
}

__global__ __launch_bounds__(256) void k_scan_add(unsigned* __restrict__ excl,
                                                  const unsigned* __restrict__ part_scan,
                                                  int n) {
    int i = blockIdx.x * 256 + threadIdx.x;
    if (i < n) excl[i] += part_scan[blockIdx.x];
}

// ---------------- pass 1b: scatter packed edges into bucket-major order ----
// packed word = (dst & 63) << 24 | src    (src < 100000 < 2^24)
__global__ __launch_bounds__(256) void k_scatter1(const int* __restrict__ src,
                                                  const int* __restrict__ dst,
                                                  const unsigned* __restrict__ hist_scan,
                                                  unsigned* __restrict__ packed) {
    __shared__ unsigned cur[NBKT];
    int t = threadIdx.x, b = blockIdx.x;
    for (int i = t; i < NBKT; i += 256) cur[i] = hist_scan[(size_t)i * NCHUNK + b];
    __syncthreads();
    int base = b * CHUNK;
    #pragma unroll 4
    for (int k = 0; k < 32; ++k) {
        int e = base + k * 256 + t;
        if (e < N_EDGES) {
            unsigned d = (unsigned)dst[e];
            unsigned pos = atomicAdd(&cur[d >> 6], 1u);   // LDS atomic
            packed[pos] = ((d & 63u) << 24) | (unsigned)src[e];
        }
    }
}

// -------- per-bucket exact-dst histogram -> deg -> dinv --------------------
__global__ __launch_bounds__(256) void k_bdeg(const unsigned* __restrict__ packed,
                                              const unsigned* __restrict__ hist_scan,
                                              float* __restrict__ dinv) {
    __shared__ unsigned hh[64];
    int t = threadIdx.x, b = blockIdx.x;
    unsigned rs = hist_scan[(size_t)b * NCHUNK];
    unsigned re = (b + 1 < NBKT) ? hist_scan[(size_t)(b + 1) * NCHUNK] : N_EDGES;
    if (t < 64) hh[t] = 0u;
    __syncthreads();
    for (unsigned i = rs + t; i < re; i += 256)
        atomicAdd(&hh[packed[i] >> 24], 1u);
    __syncthreads();
    int node = b * 64 + t;
    if (t < 64 && node < N_NODES)
        dinv[node] = rsqrtf((float)(hh[t] + 1u));
}

// ------- GEMM1: h1p = dinv .* (x@W1)  (bf16 MFMA, fp32 acc) ----------------
__global__ __launch_bounds__(256) void k_gemm1(const float* __restrict__ x,
                                               const float* __restrict__ w1,
                                               const float* __restrict__ dinv,
                                               float* __restrict__ h1p) {
    __shared__ __align__(16) short w1t[16][520];
    int tid = threadIdx.x;
    for (int idx = tid; idx < D_FEAT * HIDDEN; idx += 256) {
        int k = idx >> 4, n = idx & 15;
        w1t[n][k] = f2bf(w1[idx]);
    }
    __syncthreads();

    int lane = tid & 63, wid = tid >> 6;
    int m  = lane & 15;
    int kg = lane >> 4;

    bf16x8 bfrag[16];
    #pragma unroll
    for (int ks = 0; ks < 16; ++ks)
        bfrag[ks] = *(const bf16x8*)&w1t[m][ks * 32 + kg * 8];

    int tile = blockIdx.x * 4 + wid;
    if (tile >= (N_NODES / 16)) return;

    const f32x4* xr = (const f32x4*)(x + (size_t)(tile * 16 + m) * D_FEAT);
    f32x4 acc = {0.f, 0.f, 0.f, 0.f};
    #pragma unroll
    for (int ks = 0; ks < 16; ++ks) {
        f32x4 x0 = xr[ks * 8 + kg * 2];
        f32x4 x1 = xr[ks * 8 + kg * 2 + 1];
        bf16x8 a;
        a[0] = f2bf(x0[0]); a[1] = f2bf(x0[1]); a[2] = f2bf(x0[2]); a[3] = f2bf(x0[3]);
        a[4] = f2bf(x1[0]); a[5] = f2bf(x1[1]); a[6] = f2bf(x1[2]); a[7] = f2bf(x1[3]);
        acc = __builtin_amdgcn_mfma_f32_16x16x32_bf16(a, bfrag[ks], acc, 0, 0, 0);
    }
    // C layout: col = lane&15, row = (lane>>4)*4 + reg  [m89-verified]
    size_t base = (size_t)tile * 256;
    #pragma unroll
    for (int r = 0; r < 4; ++r) {
        int rr = kg * 4 + r;
        h1p[base + rr * 16 + m] = dinv[tile * 16 + rr] * acc[r];
    }
}

// ------- agg layer 1: LDS tile accumulate, g1 = self + sum h1p[src] --------
// One block per 64-node bucket; 16 edges in flight; ds_add_f32 accumulation.
__global__ __launch_bounds__(256) void k_agg1(const unsigned* __restrict__ packed,
                                              const unsigned* __restrict__ hist_scan,
                                              const float* __restrict__ h1p,
                                              float* __restrict__ g1) {
    __shared__ float tile[64][16];
    int t = threadIdx.x, b = blockIdx.x;
    unsigned rs = hist_scan[(size_t)b * NCHUNK];
    unsigned re = (b + 1 < NBKT) ? hist_scan[(size_t)(b + 1) * NCHUNK] : N_EDGES;

    // init with self term (h1p rows of this bucket), coalesced
    {
        int n = t >> 2, q = t & 3;            // 4 floats per thread
        int node = b * 64 + n;
        const f32x4* srcv = (const f32x4*)(h1p + (size_t)node * 16);
        f32x4 v = (node < N_NODES) ? srcv[q] : f32x4{0.f, 0.f, 0.f, 0.f};
        *(f32x4*)&tile[n][q * 4] = v;
    }
    __syncthreads();

    int j  = t & 15;
    int sl = t >> 4;                          // 0..15 -> 16 edges in flight
    unsigned i = rs + (unsigned)sl;
    for (; i + 48 < re; i += 64) {
        unsigned p0 = packed[i];
        unsigned p1 = packed[i + 16];
        unsigned p2 = packed[i + 32];
        unsigned p3 = packed[i + 48];
        float v0 = h1p[(size_t)(p0 & 0xFFFFFFu) * 16 + j];
        float v1 = h1p[(size_t)(p1 & 0xFFFFFFu) * 16 + j];
        float v2 = h1p[(size_t)(p2 & 0xFFFFFFu) * 16 + j];
        float v3 = h1p[(size_t)(p3 & 0xFFFFFFu) * 16 + j];
        atomicAdd(&tile[p0 >> 24][j], v0);
        atomicAdd(&tile[p1 >> 24][j], v1);
        atomicAdd(&tile[p2 >> 24][j], v2);
        atomicAdd(&tile[p3 >> 24][j], v3);
    }
    for (; i < re; i += 16) {
        unsigned p = packed[i];
        atomicAdd(&tile[p >> 24][j], h1p[(size_t)(p & 0xFFFFFFu) * 16 + j]);
    }
    __syncthreads();

    // flush, coalesced
    {
        int n = t >> 2, q = t & 3;
        int node = b * 64 + n;
        if (node < N_NODES)
            *(f32x4*)(g1 + (size_t)node * 16 + q * 4) = *(const f32x4*)&tile[n][q * 4];
    }
}

// ------- layer 2: h2p = dinv .* (relu(dinv.*g1 + b1) @ W2) -----------------
__global__ __launch_bounds__(256) void k_layer2(const float* __restrict__ g1,
                                                const float* __restrict__ dinv,
                                                const float* __restrict__ w2,
                                                const float* __restrict__ b1,
                                                float* __restrict__ h2p) {
    int i = blockIdx.x * 256 + threadIdx.x;
    if (i >= N_NODES) return;
    float di = dinv[i];
    const float* gr = g1 + (size_t)i * 16;
    float h[16];
    #pragma unroll
    for (int j = 0; j < 16; ++j) h[j] = fmaxf(di * gr[j] + b1[j], 0.f);
    float* h2r = h2p + (size_t)i * 8;
    #pragma unroll
    for (int c = 0; c < N_CLASSES; ++c) {
        float o = 0.f;
        #pragma unroll
        for (int j = 0; j < 16; ++j) o += h[j] * w2[j * N_CLASSES + c];
        h2r[c] = di * o;
    }
    h2r[7] = 0.f;
}

// ------- agg layer 2 + bias + log_softmax fused ----------------------------
// One block per bucket; 32 edges in flight; softmax at flush.
__global__ __launch_bounds__(256) void k_agg2(const unsigned* __restrict__ packed,
                                              const unsigned* __restrict__ hist_scan,
                                              const float* __restrict__ h2p,
                                              const float* __restrict__ dinv,
                                              const float* __restrict__ b2,
                                              float* __restrict__ out) {
    __shared__ float tile[64][8];
    int t = threadIdx.x, b = blockIdx.x;
    unsigned rs = hist_scan[(size_t)b * NCHUNK];
    unsigned re = (b + 1 < NBKT) ? hist_scan[(size_t)(b + 1) * NCHUNK] : N_EDGES;

    // init with self term
    {
        int n = t >> 2, q = t & 3;            // 2 floats per thread
        int node = b * 64 + n;
        float2 v = make_float2(0.f, 0.f);
        if (node < N_NODES) v = *(const float2*)(h2p + (size_t)node * 8 + q * 2);
        *(float2*)&tile[n][q * 2] = v;
    }
    __syncthreads();

    int j  = t & 7;
    int sl = t >> 3;                          // 0..31 -> 32 edges in flight
    unsigned i = rs + (unsigned)sl;
    for (; i + 96 < re; i += 128) {
        unsigned p0 = packed[i];
        unsigned p1 = packed[i + 32];
        unsigned p2 = packed[i + 64];
        unsigned p3 = packed[i + 96];
        float v0 = h2p[(size_t)(p0 & 0xFFFFFFu) * 8 + j];
        float v1 = h2p[(size_t)(p1 & 0xFFFFFFu) * 8 + j];
        float v2 = h2p[(size_t)(p2 & 0xFFFFFFu) * 8 + j];
        float v3 = h2p[(size_t)(p3 & 0xFFFFFFu) * 8 + j];
        atomicAdd(&tile[p0 >> 24][j], v0);
        atomicAdd(&tile[p1 >> 24][j], v1);
        atomicAdd(&tile[p2 >> 24][j], v2);
        atomicAdd(&tile[p3 >> 24][j], v3);
    }
    for (; i < re; i += 32) {
        unsigned p = packed[i];
        atomicAdd(&tile[p >> 24][j], h2p[(size_t)(p & 0xFFFFFFu) * 8 + j]);
    }
    __syncthreads();

    // log_softmax + store: one thread per node
    if (t < 64) {
        int node = b * 64 + t;
        if (node < N_NODES) {
            float di = dinv[node];
            float v[N_CLASSES];
            float mx = -1e30f;
            #pragma unroll
            for (int c = 0; c < N_CLASSES; ++c) {
                v[c] = di * tile[t][c] + b2[c];
                mx = fmaxf(mx, v[c]);
            }
            float sum = 0.f;
            #pragma unroll
            for (int c = 0; c < N_CLASSES; ++c) sum += __expf(v[c] - mx);
            float lse = __logf(sum);
            float* o = out + (size_t)node * N_CLASSES;
            #pragma unroll
            for (int c = 0; c < N_CLASSES; ++c) o[c] = v[c] - mx - lse;
        }
    }
}

extern "C" void kernel_launch(void* const* d_in, const int* in_sizes, int n_in,
                              void* d_out, int out_size, void* d_ws, size_t ws_size,
                              hipStream_t stream) {
    const float* x  = (const float*)d_in[0];
    const int*   ei = (const int*)d_in[1];
    const float* w1 = (const float*)d_in[2];
    const float* b1 = (const float*)d_in[3];
    const float* w2 = (const float*)d_in[4];
    const float* b2 = (const float*)d_in[5];
    float* out = (float*)d_out;

    const int* src = ei;
    const int* dst = ei + N_EDGES;

    // workspace carve (u32 units), ~34 MB
    unsigned* w32      = (unsigned*)d_ws;
    float*    dinv     = (float*)(w32 + 0);          // 102,400
    float*    h1p      = (float*)(w32 + 102400);     // 1,600,000
    float*    g1       = (float*)(w32 + 1702400);    // 1,600,000
    float*    h2p      = (float*)(w32 + 3302400);    //   800,000
    unsigned* hist_raw = w32 + 4102400;              // 611,200
    unsigned* hist_sc  = w32 + 4713600;              // 611,200
    unsigned* part1    = w32 + 5324800;              // 2,400
    unsigned* part2    = w32 + 5327200;              // 32
    unsigned* part2sc  = w32 + 5327232;              // 32
    unsigned* packed   = w32 + 5327264;              // 3,200,000

    const int GB = (N_NODES / 16 + 3) / 4;           // 1563 gemm blocks

    k_hist1      <<<NCHUNK, 256,  0, stream>>>(dst, hist_raw);
    // 3-level exclusive scan over 611,133 entries
    k_scan_blocks<<<NSB1,   256,  0, stream>>>(hist_raw, hist_sc, part1, NSCAN);
    k_scan_blocks<<<NSB2,   256,  0, stream>>>(part1, part1, part2, NSB1);
    k_scan_part  <<<1,      1024, 0, stream>>>(part2, part2sc, NSB2);
    k_scan_add   <<<NSB2,   256,  0, stream>>>(part1, part2sc, NSB1);
    k_scan_add   <<<NSB1,   256,  0, stream>>>(hist_sc, part1, NSCAN);
    k_scatter1   <<<NCHUNK, 256,  0, stream>>>(src, dst, hist_sc, packed);
    k_bdeg       <<<NBKT,   256,  0, stream>>>(packed, hist_sc, dinv);
    k_gemm1      <<<GB,     256,  0, stream>>>(x, w1, dinv, h1p);
    k_agg1       <<<NBKT,   256,  0, stream>>>(packed, hist_sc, h1p, g1);
    k_layer2     <<<(N_NODES + 255) / 256, 256, 0, stream>>>(g1, dinv, w2, b1, h2p);
    k_agg2       <<<NBKT,   256,  0, stream>>>(packed, hist_sc, h2p, dinv, b2, out);
}

// Round 6
// 555.145 us; speedup vs baseline: 1.5549x; 1.5549x over previous
//
#include <hip/hip_runtime.h>
#include <cmath>

#define N_NODES   100000
#define N_EDGES   3200000
#define D_FEAT    512
#define HIDDEN    16
#define N_CLASSES 7

#define NCHUNK 196                   // pass-1 blocks, 16384 edges each (limits concurrent
                                     // writers: ~25 blocks/XCD * 1563 lines = 2.5MB < 4MB L2)
#define CHUNK  16384
#define NBKT   1563                  // buckets of 64 nodes (dst>>6); 1563*64 >= 100000
#define NSCAN  (NBKT * NCHUNK)       // 306,348
#define NSB1   ((NSCAN + 255) / 256) // 1197
#define NSB2   ((NSB1 + 255) / 256)  // 5

typedef __attribute__((ext_vector_type(4))) float  f32x4;
typedef __attribute__((ext_vector_type(8))) short  bf16x8;

__device__ __forceinline__ short f2bf(float f) {
    union { float f; unsigned u; } v; v.f = f;
    unsigned r = v.u + 0x7fffu + ((v.u >> 16) & 1u);   // RNE
    return (short)(r >> 16);
}

// ---------------- pass 1a: per-chunk bucket histogram (LDS atomics only) ---
__global__ __launch_bounds__(256) void k_hist1(const int* __restrict__ dst,
                                               unsigned* __restrict__ hist) {
    __shared__ unsigned h[NBKT];
    int t = threadIdx.x, b = blockIdx.x;
    for (int i = t; i < NBKT; i += 256) h[i] = 0u;
    __syncthreads();
    int base = b * CHUNK;
    #pragma unroll 4
    for (int k = 0; k < CHUNK / 256; ++k) {
        int e = base + k * 256 + t;
        if (e < N_EDGES) atomicAdd(&h[((unsigned)dst[e]) >> 6], 1u);
    }
    __syncthreads();
    for (int i = t; i < NBKT; i += 256)
        hist[(size_t)i * NCHUNK + b] = h[i];   // bin-major for global scan
}

// ---------------- generic exclusive-scan building blocks -------------------
__global__ __launch_bounds__(256) void k_scan_blocks(const unsigned* __restrict__ in,
                                                     unsigned* __restrict__ out_excl,
                                                     unsigned* __restrict__ part, int n) {
    __shared__ unsigned t0[256];
    int t = threadIdx.x, i = blockIdx.x * 256 + t;
    unsigned v = (i < n) ? in[i] : 0u;
    t0[t] = v; __syncthreads();
    #pragma unroll
    for (int off = 1; off < 256; off <<= 1) {
        unsigned add = (t >= off) ? t0[t - off] : 0u;
        __syncthreads();
        t0[t] += add;
        __syncthreads();
    }
    if (i < n) out_excl[i] = t0[t] - v;
    if (t == 255) part[blockIdx.x] = t0[t];
}

__global__ __launch_bounds__(1024) void k_scan_part(unsigned* __restrict__ part,
                                                    unsigned* __restrict__ part_scan,
                                                    int nparts) {
    __shared__ unsigned t0[1024];
    int t = threadIdx.x;
    unsigned v = (t < nparts) ? part[t] : 0u;
    t0[t] = v; __syncthreads();
    #pragma unroll
    for (int off = 1; off < 1024; off <<= 1) {
        unsigned add = (t >= off) ? t0[t - off] : 0u;
        __syncthreads();
        t0[t] += add;
        __syncthreads();
    }
    if (t < nparts) part_scan[t] = t0[t] - v;
}

__global__ __launch_bounds__(256) void k_scan_add(unsigned* __restrict__ excl,
                                                  const unsigned* __restrict__ part_scan,
                                                  int n) {
    int i = blockIdx.x * 256 + threadIdx.x;
    if (i < n) excl[i] += part_scan[blockIdx.x];
}

// ---------------- pass 1b: scatter packed edges into bucket-major order ----
// packed word = (dst & 63) << 24 | src    (src < 100000 < 2^24)
__global__ __launch_bounds__(256) void k_scatter1(const int* __restrict__ src,
                                                  const int* __restrict__ dst,
                                                  const unsigned* __restrict__ hist_scan,
                                                  unsigned* __restrict__ packed) {
    __shared__ unsigned cur[NBKT];
    int t = threadIdx.x, b = blockIdx.x;
    for (int i = t; i < NBKT; i += 256) cur[i] = hist_scan[(size_t)i * NCHUNK + b];
    __syncthreads();
    int base = b * CHUNK;
    #pragma unroll 4
    for (int k = 0; k < CHUNK / 256; ++k) {
        int e = base + k * 256 + t;
        if (e < N_EDGES) {
            unsigned d = (unsigned)dst[e];
            unsigned pos = atomicAdd(&cur[d >> 6], 1u);   // LDS atomic
            packed[pos] = ((d & 63u) << 24) | (unsigned)src[e];
        }
    }
}

// -------- pass 2: per-bucket exact-dst sort -> deg, row_start, dinv, csr ---
// 1563 blocks, each owns 64 nodes; csr writes land in an 8KB window (L2-local)
__global__ __launch_bounds__(256) void k_bucket(const unsigned* __restrict__ packed,
                                                const unsigned* __restrict__ hist_scan,
                                                unsigned* __restrict__ deg,
                                                unsigned* __restrict__ row_start,
                                                float* __restrict__ dinv,
                                                int* __restrict__ csr_src) {
    __shared__ unsigned hh[64], sc[64], cur[64];
    int t = threadIdx.x, b = blockIdx.x;
    unsigned rs = hist_scan[(size_t)b * NCHUNK];
    unsigned re = (b + 1 < NBKT) ? hist_scan[(size_t)(b + 1) * NCHUNK] : N_EDGES;
    if (t < 64) hh[t] = 0u;
    __syncthreads();
    for (unsigned i = rs + t; i < re; i += 256)
        atomicAdd(&hh[packed[i] >> 24], 1u);
    __syncthreads();
    if (t < 64) sc[t] = hh[t];
    __syncthreads();
    #pragma unroll
    for (int off = 1; off < 64; off <<= 1) {
        unsigned add = (t >= off && t < 64) ? sc[t - off] : 0u;
        __syncthreads();
        if (t < 64) sc[t] += add;
        __syncthreads();
    }
    if (t < 64) {
        unsigned excl = sc[t] - hh[t];
        int node = b * 64 + t;
        if (node < N_NODES) {
            deg[node]       = hh[t];
            row_start[node] = rs + excl;
            dinv[node]      = rsqrtf((float)(hh[t] + 1u));
        }
        cur[t] = rs + excl;
    }
    __syncthreads();
    for (unsigned i = rs + t; i < re; i += 256) {
        unsigned p = packed[i];
        unsigned pos = atomicAdd(&cur[p >> 24], 1u);     // LDS atomic
        csr_src[pos] = (int)(p & 0xFFFFFFu);
    }
}

// ------- GEMM1: h1p = dinv .* (x@W1)  (bf16 MFMA, fp32 acc) ----------------
__global__ __launch_bounds__(256) void k_gemm1(const float* __restrict__ x,
                                               const float* __restrict__ w1,
                                               const float* __restrict__ dinv,
                                               float* __restrict__ h1p) {
    __shared__ __align__(16) short w1t[16][520];
    int tid = threadIdx.x;
    for (int idx = tid; idx < D_FEAT * HIDDEN; idx += 256) {
        int k = idx >> 4, n = idx & 15;
        w1t[n][k] = f2bf(w1[idx]);
    }
    __syncthreads();

    int lane = tid & 63, wid = tid >> 6;
    int m  = lane & 15;
    int kg = lane >> 4;

    bf16x8 bfrag[16];
    #pragma unroll
    for (int ks = 0; ks < 16; ++ks)
        bfrag[ks] = *(const bf16x8*)&w1t[m][ks * 32 + kg * 8];

    int tile = blockIdx.x * 4 + wid;
    if (tile >= (N_NODES / 16)) return;

    const f32x4* xr = (const f32x4*)(x + (size_t)(tile * 16 + m) * D_FEAT);
    f32x4 acc = {0.f, 0.f, 0.f, 0.f};
    #pragma unroll
    for (int ks = 0; ks < 16; ++ks) {
        f32x4 x0 = xr[ks * 8 + kg * 2];
        f32x4 x1 = xr[ks * 8 + kg * 2 + 1];
        bf16x8 a;
        a[0] = f2bf(x0[0]); a[1] = f2bf(x0[1]); a[2] = f2bf(x0[2]); a[3] = f2bf(x0[3]);
        a[4] = f2bf(x1[0]); a[5] = f2bf(x1[1]); a[6] = f2bf(x1[2]); a[7] = f2bf(x1[3]);
        acc = __builtin_amdgcn_mfma_f32_16x16x32_bf16(a, bfrag[ks], acc, 0, 0, 0);
    }
    // C layout: col = lane&15, row = (lane>>4)*4 + reg  [m89-verified]
    size_t base = (size_t)tile * 256;
    #pragma unroll
    for (int r = 0; r < 4; ++r) {
        int rr = kg * 4 + r;
        h1p[base + rr * 16 + m] = dinv[tile * 16 + rr] * acc[r];
    }
}

// ------- gather layer 1: g1[i][j] = h1p[i][j] + sum_e h1p[src_e][j] --------
// One wave per node; lane = slot*16 + feat; 16 edges per main iteration.
__global__ __launch_bounds__(256) void k_gather1(const int* __restrict__ csr_src,
                                                 const unsigned* __restrict__ row_start,
                                                 const unsigned* __restrict__ deg,
                                                 const float* __restrict__ h1p,
                                                 float* __restrict__ g1) {
    int tid  = threadIdx.x;
    int lane = tid & 63;
    int node = blockIdx.x * 4 + (tid >> 6);
    int j  = lane & 15;
    int sl = lane >> 4;          // 0..3

    unsigned start = row_start[node];
    unsigned end   = start + deg[node];

    float acc = (sl == 0) ? h1p[(size_t)node * 16 + j] : 0.f;   // self term
    unsigned e = start;
    for (; e + 16 <= end; e += 16) {
        int s0 = csr_src[e      + sl];
        int s1 = csr_src[e + 4  + sl];
        int s2 = csr_src[e + 8  + sl];
        int s3 = csr_src[e + 12 + sl];
        float v0 = h1p[(size_t)s0 * 16 + j];
        float v1 = h1p[(size_t)s1 * 16 + j];
        float v2 = h1p[(size_t)s2 * 16 + j];
        float v3 = h1p[(size_t)s3 * 16 + j];
        acc += v0; acc += v1; acc += v2; acc += v3;
    }
    for (; e < end; e += 4) {
        unsigned idx = e + (unsigned)sl;
        float v = 0.f;
        if (idx < end) v = h1p[(size_t)csr_src[idx] * 16 + j];
        acc += v;
    }
    acc += __shfl_down(acc, 32);
    acc += __shfl_down(acc, 16);
    if (sl == 0) g1[(size_t)node * 16 + j] = acc;
}

// ------- layer 2: h2p = dinv .* (relu(dinv.*g1 + b1) @ W2) -----------------
__global__ __launch_bounds__(256) void k_layer2(const float* __restrict__ g1,
                                                const float* __restrict__ dinv,
                                                const float* __restrict__ w2,
                                                const float* __restrict__ b1,
                                                float* __restrict__ h2p) {
    int i = blockIdx.x * 256 + threadIdx.x;
    if (i >= N_NODES) return;
    float di = dinv[i];
    const float* gr = g1 + (size_t)i * 16;
    float h[16];
    #pragma unroll
    for (int j = 0; j < 16; ++j) h[j] = fmaxf(di * gr[j] + b1[j], 0.f);
    float* h2r = h2p + (size_t)i * 8;
    #pragma unroll
    for (int c = 0; c < N_CLASSES; ++c) {
        float o = 0.f;
        #pragma unroll
        for (int j = 0; j < 16; ++j) o += h[j] * w2[j * N_CLASSES + c];
        h2r[c] = di * o;
    }
    h2r[7] = 0.f;
}

// ------- gather layer 2 + bias + log_softmax fused -------------------------
// One wave per node; lane = slot*8 + class; 32 edges per main iteration.
__global__ __launch_bounds__(256) void k_gather2(const int* __restrict__ csr_src,
                                                 const unsigned* __restrict__ row_start,
                                                 const unsigned* __restrict__ deg,
                                                 const float* __restrict__ dinv,
                                                 const float* __restrict__ h2p,
                                                 const float* __restrict__ b2,
                                                 float* __restrict__ out) {
    int tid  = threadIdx.x;
    int lane = tid & 63;
    int node = blockIdx.x * 4 + (tid >> 6);
    int j  = lane & 7;
    int sl = lane >> 3;          // 0..7

    unsigned start = row_start[node];
    unsigned end   = start + deg[node];

    float acc = (sl == 0) ? h2p[(size_t)node * 8 + j] : 0.f;    // self term
    unsigned e = start;
    for (; e + 32 <= end; e += 32) {
        int s0 = csr_src[e      + sl];
        int s1 = csr_src[e + 8  + sl];
        int s2 = csr_src[e + 16 + sl];
        int s3 = csr_src[e + 24 + sl];
        float v0 = h2p[(size_t)s0 * 8 + j];
        float v1 = h2p[(size_t)s1 * 8 + j];
        float v2 = h2p[(size_t)s2 * 8 + j];
        float v3 = h2p[(size_t)s3 * 8 + j];
        acc += v0; acc += v1; acc += v2; acc += v3;
    }
    for (; e < end; e += 8) {
        unsigned idx = e + (unsigned)sl;
        float v = 0.f;
        if (idx < end) v = h2p[(size_t)csr_src[idx] * 8 + j];
        acc += v;
    }
    acc += __shfl_down(acc, 32);
    acc += __shfl_down(acc, 16);
    acc += __shfl_down(acc, 8);
    // lanes 0..7 now hold the aggregate for classes 0..7 (class 7 slot = 0)
    float di = dinv[node];
    float logit = (j < N_CLASSES) ? di * acc + b2[j] : -1e30f;
    float mx = logit;
    #pragma unroll
    for (int mk = 1; mk < 8; mk <<= 1) mx = fmaxf(mx, __shfl_xor(mx, mk, 8));
    float ex = (j < N_CLASSES) ? __expf(logit - mx) : 0.f;
    float sum = ex;
    #pragma unroll
    for (int mk = 1; mk < 8; mk <<= 1) sum += __shfl_xor(sum, mk, 8);
    if (sl == 0 && j < N_CLASSES)
        out[(size_t)node * N_CLASSES + j] = logit - mx - __logf(sum);
}

extern "C" void kernel_launch(void* const* d_in, const int* in_sizes, int n_in,
                              void* d_out, int out_size, void* d_ws, size_t ws_size,
                              hipStream_t stream) {
    const float* x  = (const float*)d_in[0];
    const int*   ei = (const int*)d_in[1];
    const float* w1 = (const float*)d_in[2];
    const float* b1 = (const float*)d_in[3];
    const float* w2 = (const float*)d_in[4];
    const float* b2 = (const float*)d_in[5];
    float* out = (float*)d_out;

    const int* src = ei;
    const int* dst = ei + N_EDGES;

    // workspace carve (u32 units), ~43 MB
    unsigned* w32       = (unsigned*)d_ws;
    float*    dinv      = (float*)(w32 + 0);          // 102,400
    float*    h1p       = (float*)(w32 + 102400);     // 1,600,000
    float*    g1        = (float*)(w32 + 1702400);    // 1,600,000
    unsigned* deg       = w32 + 3302400;              // 102,400
    unsigned* row_start = w32 + 3404800;              // 102,400
    unsigned* hist_raw  = w32 + 3507200;              // 306,432
    unsigned* hist_sc   = w32 + 3813632;              // 306,432
    unsigned* part1     = w32 + 4120064;              // 1,280
    unsigned* part2     = w32 + 4121344;              // 32
    unsigned* part2sc   = w32 + 4121376;              // 32
    unsigned* packed    = w32 + 4121408;              // 3,200,000
    int*      csr_src   = (int*)(w32 + 7321408);      // 3,200,000
    float*    h2p       = (float*)packed;             // alias: packed free after k_bucket

    const int GB = (N_NODES / 16 + 3) / 4;            // 1563 gemm blocks

    k_hist1      <<<NCHUNK, 256,  0, stream>>>(dst, hist_raw);
    // 3-level exclusive scan over 306,348 entries
    k_scan_blocks<<<NSB1,   256,  0, stream>>>(hist_raw, hist_sc, part1, NSCAN);
    k_scan_blocks<<<NSB2,   256,  0, stream>>>(part1, part1, part2, NSB1);
    k_scan_part  <<<1,      1024, 0, stream>>>(part2, part2sc, NSB2);
    k_scan_add   <<<NSB2,   256,  0, stream>>>(part1, part2sc, NSB1);
    k_scan_add   <<<NSB1,   256,  0, stream>>>(hist_sc, part1, NSCAN);
    k_scatter1   <<<NCHUNK, 256,  0, stream>>>(src, dst, hist_sc, packed);
    k_bucket     <<<NBKT,   256,  0, stream>>>(packed, hist_sc, deg, row_start, dinv, csr_src);
    k_gemm1      <<<GB,     256,  0, stream>>>(x, w1, dinv, h1p);
    k_gather1    <<<25000,  256,  0, stream>>>(csr_src, row_start, deg, h1p, g1);
    k_layer2     <<<(N_NODES + 255) / 256, 256, 0, stream>>>(g1, dinv, w2, b1, h2p);
    k_gather2    <<<25000,  256,  0, stream>>>(csr_src, row_start, deg, dinv, h2p, b2, out);
}

// Round 7
// 490.805 us; speedup vs baseline: 1.7587x; 1.1311x over previous
//
#include <hip/hip_runtime.h>
#include <cmath>

#define N_NODES   100000
#define N_EDGES   3200000
#define D_FEAT    512
#define HIDDEN    16
#define N_CLASSES 7

#define NCHUNK 250                   // pass-1 blocks of 1024 thr; 250*12800 = 3.2M exactly
#define CHUNK  12800
#define NBKT   1563                  // buckets of 64 nodes (dst>>6)
#define NSCAN  (NBKT * NCHUNK)       // 390,750

typedef __attribute__((ext_vector_type(4))) float  f32x4;
typedef __attribute__((ext_vector_type(8))) short  bf16x8;

__device__ __forceinline__ short f2bf(float f) {
    union { float f; unsigned u; } v; v.f = f;
    unsigned r = v.u + 0x7fffu + ((v.u >> 16) & 1u);   // RNE
    return (short)(r >> 16);
}
__device__ __forceinline__ float bf2f(unsigned short s) {
    union { unsigned u; float f; } v; v.u = ((unsigned)s) << 16;
    return v.f;
}

// ---------------- pass 1a: per-chunk bucket histogram (LDS atomics only) ---
__global__ __launch_bounds__(1024) void k_hist1(const int* __restrict__ dst,
                                                unsigned* __restrict__ hist) {
    __shared__ unsigned h[NBKT];
    int t = threadIdx.x, b = blockIdx.x;
    for (int i = t; i < NBKT; i += 1024) h[i] = 0u;
    __syncthreads();
    int base = b * CHUNK;
    #pragma unroll 2
    for (int k = 0; k < 13; ++k) {
        int idx = k * 1024 + t;
        if (idx < CHUNK) atomicAdd(&h[((unsigned)dst[base + idx]) >> 6], 1u);
    }
    __syncthreads();
    for (int i = t; i < NBKT; i += 1024)
        hist[(size_t)i * NCHUNK + b] = h[i];   // bin-major
}

// -------- scan A: per-bin exclusive scan of its NCHUNK entries (in place) --
__global__ __launch_bounds__(256) void k_scan_a(unsigned* __restrict__ hist,
                                                unsigned* __restrict__ bin_total) {
    __shared__ unsigned t0[256];
    int t = threadIdx.x, b = blockIdx.x;
    unsigned v = (t < NCHUNK) ? hist[(size_t)b * NCHUNK + t] : 0u;
    t0[t] = v; __syncthreads();
    #pragma unroll
    for (int off = 1; off < 256; off <<= 1) {
        unsigned add = (t >= off) ? t0[t - off] : 0u;
        __syncthreads();
        t0[t] += add;
        __syncthreads();
    }
    if (t < NCHUNK) hist[(size_t)b * NCHUNK + t] = t0[t] - v;   // excl within bin
    if (t == 255) bin_total[b] = t0[t];
}

// -------- scan B: exclusive scan of 1563 bin totals (single block) ---------
__global__ __launch_bounds__(256) void k_scan_b(const unsigned* __restrict__ bin_total,
                                                unsigned* __restrict__ bin_base) {
    __shared__ unsigned t0[256];
    int t = threadIdx.x;
    unsigned running = 0u;
    for (int c0 = 0; c0 < NBKT; c0 += 256) {
        int i = c0 + t;
        unsigned v = (i < NBKT) ? bin_total[i] : 0u;
        t0[t] = v; __syncthreads();
        #pragma unroll
        for (int off = 1; off < 256; off <<= 1) {
            unsigned add = (t >= off) ? t0[t - off] : 0u;
            __syncthreads();
            t0[t] += add;
            __syncthreads();
        }
        if (i < NBKT) bin_base[i] = running + t0[t] - v;
        unsigned chunk_sum = t0[255];
        __syncthreads();          // protect t0 before next-iteration overwrite
        running += chunk_sum;
    }
    if (t == 0) bin_base[NBKT] = running;   // == N_EDGES
}

// ---------------- pass 1b: scatter packed edges into bucket-major order ----
// packed word = (dst & 63) << 24 | src    (src < 100000 < 2^24)
__global__ __launch_bounds__(1024) void k_scatter1(const int* __restrict__ src,
                                                   const int* __restrict__ dst,
                                                   const unsigned* __restrict__ hist,
                                                   const unsigned* __restrict__ bin_base,
                                                   unsigned* __restrict__ packed) {
    __shared__ unsigned cur[NBKT];
    int t = threadIdx.x, b = blockIdx.x;
    for (int i = t; i < NBKT; i += 1024)
        cur[i] = hist[(size_t)i * NCHUNK + b] + bin_base[i];
    __syncthreads();
    int base = b * CHUNK;
    #pragma unroll 2
    for (int k = 0; k < 13; ++k) {
        int idx = k * 1024 + t;
        if (idx < CHUNK) {
            int e = base + idx;
            unsigned d = (unsigned)dst[e];
            unsigned pos = atomicAdd(&cur[d >> 6], 1u);   // LDS atomic
            packed[pos] = ((d & 63u) << 24) | (unsigned)src[e];
        }
    }
}

// -------- pass 2: per-bucket exact-dst sort -> deg, row_start, dinv, csr ---
__global__ __launch_bounds__(256) void k_bucket(const unsigned* __restrict__ packed,
                                                const unsigned* __restrict__ bin_base,
                                                unsigned* __restrict__ deg,
                                                unsigned* __restrict__ row_start,
                                                float* __restrict__ dinv,
                                                int* __restrict__ csr_src) {
    __shared__ unsigned hh[4][64], sc[64], cur[64];
    int t = threadIdx.x, b = blockIdx.x;
    int w = t >> 6, l = t & 63;
    unsigned rs = bin_base[b];
    unsigned re = bin_base[b + 1];
    hh[w][l] = 0u;
    __syncthreads();
    for (unsigned i = rs + t; i < re; i += 256)
        atomicAdd(&hh[w][packed[i] >> 24], 1u);    // per-wave sub-hist
    __syncthreads();
    unsigned total = 0u;
    if (t < 64) {
        total = hh[0][t] + hh[1][t] + hh[2][t] + hh[3][t];
        sc[t] = total;
    }
    __syncthreads();
    #pragma unroll
    for (int off = 1; off < 64; off <<= 1) {
        unsigned add = (t >= off && t < 64) ? sc[t - off] : 0u;
        __syncthreads();
        if (t < 64) sc[t] += add;
        __syncthreads();
    }
    if (t < 64) {
        unsigned excl = sc[t] - total;
        int node = b * 64 + t;
        if (node < N_NODES) {
            deg[node]       = total;
            row_start[node] = rs + excl;
            dinv[node]      = rsqrtf((float)(total + 1u));
        }
        cur[t] = rs + excl;
    }
    __syncthreads();
    for (unsigned i = rs + t; i < re; i += 256) {
        unsigned p = packed[i];
        unsigned pos = atomicAdd(&cur[p >> 24], 1u);     // LDS atomic
        csr_src[pos] = (int)(p & 0xFFFFFFu);
    }
}

// ------- GEMM1: h1p = bf16( dinv .* (x@W1) )  (bf16 MFMA, fp32 acc) --------
__global__ __launch_bounds__(256) void k_gemm1(const float* __restrict__ x,
                                               const float* __restrict__ w1,
                                               const float* __restrict__ dinv,
                                               unsigned short* __restrict__ h1p) {
    __shared__ __align__(16) short w1t[16][520];
    int tid = threadIdx.x;
    for (int idx = tid; idx < D_FEAT * HIDDEN; idx += 256) {
        int k = idx >> 4, n = idx & 15;
        w1t[n][k] = f2bf(w1[idx]);
    }
    __syncthreads();

    int lane = tid & 63, wid = tid >> 6;
    int m  = lane & 15;
    int kg = lane >> 4;

    bf16x8 bfrag[16];
    #pragma unroll
    for (int ks = 0; ks < 16; ++ks)
        bfrag[ks] = *(const bf16x8*)&w1t[m][ks * 32 + kg * 8];

    int tile = blockIdx.x * 4 + wid;
    if (tile >= (N_NODES / 16)) return;

    const f32x4* xr = (const f32x4*)(x + (size_t)(tile * 16 + m) * D_FEAT);
    f32x4 acc = {0.f, 0.f, 0.f, 0.f};
    #pragma unroll
    for (int ks = 0; ks < 16; ++ks) {
        f32x4 x0 = xr[ks * 8 + kg * 2];
        f32x4 x1 = xr[ks * 8 + kg * 2 + 1];
        bf16x8 a;
        a[0] = f2bf(x0[0]); a[1] = f2bf(x0[1]); a[2] = f2bf(x0[2]); a[3] = f2bf(x0[3]);
        a[4] = f2bf(x1[0]); a[5] = f2bf(x1[1]); a[6] = f2bf(x1[2]); a[7] = f2bf(x1[3]);
        acc = __builtin_amdgcn_mfma_f32_16x16x32_bf16(a, bfrag[ks], acc, 0, 0, 0);
    }
    // C layout: col = lane&15, row = (lane>>4)*4 + reg  [m89-verified]
    size_t base = (size_t)tile * 256;
    #pragma unroll
    for (int r = 0; r < 4; ++r) {
        int rr = kg * 4 + r;
        h1p[base + rr * 16 + m] = (unsigned short)f2bf(dinv[tile * 16 + rr] * acc[r]);
    }
}

// ------- gather layer 1: g1[i][j] = h1p[i][j] + sum_e h1p[src_e][j] --------
// One wave per node; lane = slot*16 + feat; 16 edges per main iteration.
__global__ __launch_bounds__(256) void k_gather1(const int* __restrict__ csr_src,
                                                 const unsigned* __restrict__ row_start,
                                                 const unsigned* __restrict__ deg,
                                                 const unsigned short* __restrict__ h1p,
                                                 float* __restrict__ g1) {
    int tid  = threadIdx.x;
    int lane = tid & 63;
    int node = blockIdx.x * 4 + (tid >> 6);
    int j  = lane & 15;
    int sl = lane >> 4;          // 0..3

    unsigned start = row_start[node];
    unsigned end   = start + deg[node];

    float acc = (sl == 0) ? bf2f(h1p[(size_t)node * 16 + j]) : 0.f;   // self term
    unsigned e = start;
    for (; e + 16 <= end; e += 16) {
        int s0 = csr_src[e      + sl];
        int s1 = csr_src[e + 4  + sl];
        int s2 = csr_src[e + 8  + sl];
        int s3 = csr_src[e + 12 + sl];
        float v0 = bf2f(h1p[(size_t)s0 * 16 + j]);
        float v1 = bf2f(h1p[(size_t)s1 * 16 + j]);
        float v2 = bf2f(h1p[(size_t)s2 * 16 + j]);
        float v3 = bf2f(h1p[(size_t)s3 * 16 + j]);
        acc += v0; acc += v1; acc += v2; acc += v3;
    }
    for (; e < end; e += 4) {
        unsigned idx = e + (unsigned)sl;
        float v = 0.f;
        if (idx < end) v = bf2f(h1p[(size_t)csr_src[idx] * 16 + j]);
        acc += v;
    }
    acc += __shfl_down(acc, 32);
    acc += __shfl_down(acc, 16);
    if (sl == 0) g1[(size_t)node * 16 + j] = acc;
}

// ------- layer 2: h2p = dinv .* (relu(dinv.*g1 + b1) @ W2) -----------------
__global__ __launch_bounds__(256) void k_layer2(const float* __restrict__ g1,
                                                const float* __restrict__ dinv,
                                                const float* __restrict__ w2,
                                                const float* __restrict__ b1,
                                                float* __restrict__ h2p) {
    int i = blockIdx.x * 256 + threadIdx.x;
    if (i >= N_NODES) return;
    float di = dinv[i];
    const float* gr = g1 + (size_t)i * 16;
    float h[16];
    #pragma unroll
    for (int j = 0; j < 16; ++j) h[j] = fmaxf(di * gr[j] + b1[j], 0.f);
    float* h2r = h2p + (size_t)i * 8;
    #pragma unroll
    for (int c = 0; c < N_CLASSES; ++c) {
        float o = 0.f;
        #pragma unroll
        for (int j = 0; j < 16; ++j) o += h[j] * w2[j * N_CLASSES + c];
        h2r[c] = di * o;
    }
    h2r[7] = 0.f;
}

// ------- gather layer 2 + bias + log_softmax fused -------------------------
// One wave per node; lane = slot*8 + class; 32 edges per main iteration.
__global__ __launch_bounds__(256) void k_gather2(const int* __restrict__ csr_src,
                                                 const unsigned* __restrict__ row_start,
                                                 const unsigned* __restrict__ deg,
                                                 const float* __restrict__ dinv,
                                                 const float* __restrict__ h2p,
                                                 const float* __restrict__ b2,
                                                 float* __restrict__ out) {
    int tid  = threadIdx.x;
    int lane = tid & 63;
    int node = blockIdx.x * 4 + (tid >> 6);
    int j  = lane & 7;
    int sl = lane >> 3;          // 0..7

    unsigned start = row_start[node];
    unsigned end   = start + deg[node];

    float acc = (sl == 0) ? h2p[(size_t)node * 8 + j] : 0.f;    // self term
    unsigned e = start;
    for (; e + 32 <= end; e += 32) {
        int s0 = csr_src[e      + sl];
        int s1 = csr_src[e + 8  + sl];
        int s2 = csr_src[e + 16 + sl];
        int s3 = csr_src[e + 24 + sl];
        float v0 = h2p[(size_t)s0 * 8 + j];
        float v1 = h2p[(size_t)s1 * 8 + j];
        float v2 = h2p[(size_t)s2 * 8 + j];
        float v3 = h2p[(size_t)s3 * 8 + j];
        acc += v0; acc += v1; acc += v2; acc += v3;
    }
    for (; e < end; e += 8) {
        unsigned idx = e + (unsigned)sl;
        float v = 0.f;
        if (idx < end) v = h2p[(size_t)csr_src[idx] * 8 + j];
        acc += v;
    }
    acc += __shfl_down(acc, 32);
    acc += __shfl_down(acc, 16);
    acc += __shfl_down(acc, 8);
    float di = dinv[node];
    float logit = (j < N_CLASSES) ? di * acc + b2[j] : -1e30f;
    float mx = logit;
    #pragma unroll
    for (int mk = 1; mk < 8; mk <<= 1) mx = fmaxf(mx, __shfl_xor(mx, mk, 8));
    float ex = (j < N_CLASSES) ? __expf(logit - mx) : 0.f;
    float sum = ex;
    #pragma unroll
    for (int mk = 1; mk < 8; mk <<= 1) sum += __shfl_xor(sum, mk, 8);
    if (sl == 0 && j < N_CLASSES)
        out[(size_t)node * N_CLASSES + j] = logit - mx - __logf(sum);
}

extern "C" void kernel_launch(void* const* d_in, const int* in_sizes, int n_in,
                              void* d_out, int out_size, void* d_ws, size_t ws_size,
                              hipStream_t stream) {
    const float* x  = (const float*)d_in[0];
    const int*   ei = (const int*)d_in[1];
    const float* w1 = (const float*)d_in[2];
    const float* b1 = (const float*)d_in[3];
    const float* w2 = (const float*)d_in[4];
    const float* b2 = (const float*)d_in[5];
    float* out = (float*)d_out;

    const int* src = ei;
    const int* dst = ei + N_EDGES;

    // workspace carve (u32 units), ~41 MB
    unsigned* w32        = (unsigned*)d_ws;
    float*    dinv       = (float*)(w32 + 0);          // 102,400
    unsigned short* h1p  = (unsigned short*)(w32 + 102400);   // 1.6M ushort = 800,000 u32
    float*    g1         = (float*)(w32 + 902400);     // 1,600,000
    float*    h2p        = (float*)(w32 + 2502400);    //   800,000
    unsigned* deg        = w32 + 3302400;              // 102,400
    unsigned* row_start  = w32 + 3404800;              // 102,400
    unsigned* hist       = w32 + 3507200;              // 390,784
    unsigned* bin_total  = w32 + 3897984;              // 1,568
    unsigned* bin_base   = w32 + 3899552;              // 1,568
    unsigned* packed     = w32 + 3901120;              // 3,200,000
    int*      csr_src    = (int*)(w32 + 7101120);      // 3,200,000

    const int GB = (N_NODES / 16 + 3) / 4;             // 1563 gemm blocks

    k_hist1   <<<NCHUNK, 1024, 0, stream>>>(dst, hist);
    k_scan_a  <<<NBKT,   256,  0, stream>>>(hist, bin_total);
    k_scan_b  <<<1,      256,  0, stream>>>(bin_total, bin_base);
    k_scatter1<<<NCHUNK, 1024, 0, stream>>>(src, dst, hist, bin_base, packed);
    k_bucket  <<<NBKT,   256,  0, stream>>>(packed, bin_base, deg, row_start, dinv, csr_src);
    k_gemm1   <<<GB,     256,  0, stream>>>(x, w1, dinv, h1p);
    k_gather1 <<<25000,  256,  0, stream>>>(csr_src, row_start, deg, h1p, g1);
    k_layer2  <<<(N_NODES + 255) / 256, 256, 0, stream>>>(g1, dinv, w2, b1, h2p);
    k_gather2 <<<25000,  256,  0, stream>>>(csr_src, row_start, deg, dinv, h2p, b2, out);
}